// Round 4
// baseline (1326.092 us; speedup 1.0000x reference)
//
#include <hip/hip_runtime.h>
#include <hip/hip_fp16.h>
#include <math.h>

#define C 16
#define FIN 128

typedef unsigned int u32x2 __attribute__((ext_vector_type(2)));

// ---------------- GEMM x@W1 (100k x 128 x 16) + fused a_s/a_d ----------------
// h is stored as fp16 rows (32B) so the gather working set (3.2MB) fits a 4MiB
// per-XCD L2. a_s/a_d stay fp32 (exact logits).
__global__ __launch_bounds__(256) void k_gemm1(
    const float* __restrict__ x, const float* __restrict__ W,
    const float* __restrict__ asw, const float* __restrict__ adw,
    __half* __restrict__ hh, float* __restrict__ a_s, float* __restrict__ a_d, int n) {
  __shared__ float xs[64 * 129];
  __shared__ float Ws[FIN * C];
  __shared__ float pAs[4][64], pAd[4][64];
  int t = threadIdx.x;
  int node0 = blockIdx.x * 64;
  for (int i = t; i < FIN * C; i += 256) Ws[i] = W[i];
  for (int i = t; i < 64 * FIN; i += 256) {
    int r = i >> 7, c = i & 127;
    int node = node0 + r;
    xs[r * 129 + c] = (node < n) ? x[(size_t)node * FIN + c] : 0.f;
  }
  __syncthreads();
  int nn = t & 63, cg = (t >> 6) * 4, grp = t >> 6;
  float a0 = 0.f, a1 = 0.f, a2 = 0.f, a3 = 0.f;
  const float* xr = &xs[nn * 129];
  #pragma unroll 8
  for (int k = 0; k < FIN; ++k) {
    float xv = xr[k];
    const float* wr = &Ws[k * C + cg];
    a0 += xv * wr[0]; a1 += xv * wr[1]; a2 += xv * wr[2]; a3 += xv * wr[3];
  }
  int node = node0 + nn;
  if (node < n) {
    __half2 p0 = __floats2half2_rn(a0, a1), p1 = __floats2half2_rn(a2, a3);
    unsigned u0, u1;
    memcpy(&u0, &p0, 4); memcpy(&u1, &p1, 4);
    *(uint2*)(hh + (size_t)node * 16 + cg) = make_uint2(u0, u1);
  }
  pAs[grp][nn] = a0 * asw[cg] + a1 * asw[cg + 1] + a2 * asw[cg + 2] + a3 * asw[cg + 3];
  pAd[grp][nn] = a0 * adw[cg] + a1 * adw[cg + 1] + a2 * adw[cg + 2] + a3 * adw[cg + 3];
  __syncthreads();
  if (t < 64 && node0 + t < n) {
    a_s[node0 + t] = pAs[0][t] + pAs[1][t] + pAs[2][t] + pAs[3][t];
    a_d[node0 + t] = pAd[0][t] + pAd[1][t] + pAd[2][t] + pAd[3][t];
  }
}

// ---------------- CSR build ----------------
__global__ __launch_bounds__(256) void k_hist_rank(
    const int* __restrict__ dst, int* __restrict__ counts,
    int* __restrict__ rank, int ne) {
  int e = blockIdx.x * 256 + threadIdx.x;
  if (e < ne) rank[e] = atomicAdd(&counts[dst[e]], 1);
}

__global__ __launch_bounds__(512) void k_scan1(const int* __restrict__ counts,
                                               int* __restrict__ bsum, int n) {
  __shared__ int sd[512];
  int i = blockIdx.x * 512 + threadIdx.x;
  sd[threadIdx.x] = (i < n) ? counts[i] : 0;
  __syncthreads();
  for (int s = 256; s > 0; s >>= 1) {
    if (threadIdx.x < s) sd[threadIdx.x] += sd[threadIdx.x + s];
    __syncthreads();
  }
  if (threadIdx.x == 0) bsum[blockIdx.x] = sd[0];
}

__global__ __launch_bounds__(512) void k_scan2(int* __restrict__ bsum,
                                               int* __restrict__ offs,
                                               int nblk, int n) {
  __shared__ int sd[512];
  int t = threadIdx.x;
  int v = (t < nblk) ? bsum[t] : 0;
  sd[t] = v;
  __syncthreads();
  for (int off = 1; off < 512; off <<= 1) {
    int x = (t >= off) ? sd[t - off] : 0;
    __syncthreads();
    sd[t] += x;
    __syncthreads();
  }
  if (t < nblk) bsum[t] = sd[t] - v;
  if (t == nblk - 1) offs[n] = sd[t];
}

__global__ __launch_bounds__(512) void k_scan3(const int* __restrict__ counts,
                                               const int* __restrict__ bsum,
                                               int* __restrict__ offs, int n) {
  __shared__ int sd[512];
  int t = threadIdx.x;
  int i = blockIdx.x * 512 + t;
  int v = (i < n) ? counts[i] : 0;
  sd[t] = v;
  __syncthreads();
  for (int off = 1; off < 512; off <<= 1) {
    int x = (t >= off) ? sd[t - off] : 0;
    __syncthreads();
    sd[t] += x;
    __syncthreads();
  }
  if (i < n) offs[i] = bsum[blockIdx.x] + sd[t] - v;
}

// Precompute per-edge attention scalars for BOTH layers: s_l = ea . we_l.
// (The self-loop mean-attr term is linear, so mean(ea).we = mean(ea.we) --
// only the scalar is ever needed.)
__global__ __launch_bounds__(256) void k_scatter(
    const int* __restrict__ src, const int* __restrict__ dst,
    const float2* __restrict__ ea, const int* __restrict__ offs,
    const int* __restrict__ rank,
    const float* __restrict__ We1, const float* __restrict__ ae1,
    const float* __restrict__ We2, const float* __restrict__ ae2,
    uint2* __restrict__ bucket, int ne) {
  int e = blockIdx.x * 256 + threadIdx.x;
  if (e >= ne) return;
  float w01 = 0.f, w11 = 0.f, w02 = 0.f, w12 = 0.f;
  #pragma unroll
  for (int c = 0; c < C; ++c) {
    w01 += We1[c] * ae1[c]; w11 += We1[C + c] * ae1[c];
    w02 += We2[c] * ae2[c]; w12 += We2[C + c] * ae2[c];
  }
  int d = dst[e];
  float2 a = ea[e];
  __half2 hp = __floats2half2_rn(a.x * w01 + a.y * w11, a.x * w02 + a.y * w12);
  unsigned hb;
  memcpy(&hb, &hp, 4);
  bucket[offs[d] + rank[e]] = make_uint2((unsigned)src[e], hb);
}

// ---------------- per-node gather: ONE WAVE per node, 2 lanes per edge ------
// 32 edge slots per wave -> avg degree 32 collapses to ONE iteration: the
// coalesced 256B bucket read, then ALL 32 edges' hh gathers (32 lines) and
// a_s gathers are in flight concurrently. No serial dependent-iteration chain
// (rounds 0-3 were pinned at ~192us by exactly that chain: FETCH dropped
// 122->41MB with zero effect on time). Pair reduce = 5-step shfl_xor tree.
__global__ __launch_bounds__(256) void k_gather(
    const uint2* __restrict__ bucket, const int* __restrict__ offs,
    const float* __restrict__ a_s, const float* __restrict__ a_d,
    const __half* __restrict__ hh, const float* __restrict__ bias,
    float* __restrict__ outv, float* __restrict__ bnsum, float* __restrict__ bnsq,
    int lay, int do_bn, int n) {
  __shared__ float sbn[32];
  int t = threadIdx.x;
  if (t < 32) sbn[t] = 0.f;
  __syncthreads();

  int node = blockIdx.x * 4 + (t >> 6);
  int l = t & 63, p = l >> 1, f = l & 1;

  float acc[8];
  #pragma unroll
  for (int j = 0; j < 8; ++j) acc[j] = 0.f;
  float den = 0.f, ssum = 0.f;
  int o0 = 0, o1 = 0;
  float adi = 0.f, asi = 0.f;
  if (node < n) {
    o0 = offs[node]; o1 = offs[node + 1];
    adi = a_d[node]; asi = a_s[node];
    for (int base = o0; base < o1; base += 32) {   // wave-uniform trip count
      int e = base + p;
      bool val = e < o1;
      int ee = val ? e : (o1 - 1);
      u32x2 r = __builtin_nontemporal_load((const u32x2*)(bucket + ee));
      int s = (int)r.x;
      unsigned scb = r.y;
      __half2 sc2;
      memcpy(&sc2, &scb, 4);
      float se = lay ? __high2float(sc2) : __low2float(sc2);
      float asv = a_s[s];
      uint4 hv = *(const uint4*)(hh + ((size_t)s << 4) + (f << 3));
      float lg = asv + adi + se;
      lg = lg > 0.f ? lg : 0.2f * lg;
      float ex = val ? __expf(lg) : 0.f;
      den += ex;
      ssum += val ? se : 0.f;
      __half2 t0, t1, t2, t3;
      memcpy(&t0, &hv.x, 4); memcpy(&t1, &hv.y, 4);
      memcpy(&t2, &hv.z, 4); memcpy(&t3, &hv.w, 4);
      float2 g0 = __half22float2(t0), g1 = __half22float2(t1);
      float2 g2 = __half22float2(t2), g3 = __half22float2(t3);
      acc[0] += ex * g0.x; acc[1] += ex * g0.y;
      acc[2] += ex * g1.x; acc[3] += ex * g1.y;
      acc[4] += ex * g2.x; acc[5] += ex * g2.y;
      acc[6] += ex * g3.x; acc[7] += ex * g3.y;
    }
  }
  // reduce over the 32 pairs (lane bits 1..5); f-chains stay separate so each
  // channel-half keeps its own sums; den/ssum are per-f duplicates (correct).
  #pragma unroll
  for (int off = 2; off <= 32; off <<= 1) {
    den += __shfl_xor(den, off);
    ssum += __shfl_xor(ssum, off);
    #pragma unroll
    for (int j = 0; j < 8; ++j) acc[j] += __shfl_xor(acc[j], off);
  }

  float v[8];
  #pragma unroll
  for (int j = 0; j < 8; ++j) v[j] = 0.f;
  if (node < n) {
    float dgc = fmaxf((float)(o1 - o0), 1.f);
    float lg = asi + adi + ssum / dgc;
    lg = lg > 0.f ? lg : 0.2f * lg;
    float exs = __expf(lg);
    uint4 hv = *(const uint4*)(hh + ((size_t)node << 4) + (f << 3));
    __half2 t0, t1, t2, t3;
    memcpy(&t0, &hv.x, 4); memcpy(&t1, &hv.y, 4);
    memcpy(&t2, &hv.z, 4); memcpy(&t3, &hv.w, 4);
    float2 g0 = __half22float2(t0), g1 = __half22float2(t1);
    float2 g2 = __half22float2(t2), g3 = __half22float2(t3);
    float hs[8] = {g0.x, g0.y, g1.x, g1.y, g2.x, g2.y, g3.x, g3.y};
    float inv = 1.f / (den + exs);
    const float* bp = bias + f * 8;
    #pragma unroll
    for (int j = 0; j < 8; ++j)
      v[j] = fmaxf((acc[j] + exs * hs[j]) * inv + bp[j], 0.f);
    if (p == 0) {
      float4* op = (float4*)(outv + ((size_t)node << 4));
      op[f * 2]     = make_float4(v[0], v[1], v[2], v[3]);
      op[f * 2 + 1] = make_float4(v[4], v[5], v[6], v[7]);
    }
  }

  if (do_bn) {
    bool act = (node < n) && (p == 0);
    if (act) {
      #pragma unroll
      for (int j = 0; j < 8; ++j) {
        atomicAdd(&sbn[f * 8 + j], v[j]);
        atomicAdd(&sbn[16 + f * 8 + j], v[j] * v[j]);
      }
    }
    __syncthreads();
    if (t < 16) atomicAdd(&bnsum[t], sbn[t]);
    else if (t < 32) atomicAdd(&bnsq[t - 16], sbn[t]);
  }
}

__global__ void k_bnp(const float* __restrict__ bnsum, const float* __restrict__ bnsq,
                      const float* __restrict__ g, const float* __restrict__ bb,
                      float* __restrict__ scale, float* __restrict__ shift, float invn) {
  int c = threadIdx.x;
  if (c >= C) return;
  float mean = bnsum[c] * invn;
  float var = bnsq[c] * invn - mean * mean;
  float s = g[c] * rsqrtf(var + 1e-5f);
  scale[c] = s; shift[c] = bb[c] - mean * s;
}

// ---------------- BN + 16x16 matmul + a_s/a_d for layer 2 ----------------
__global__ __launch_bounds__(256) void k_node2(
    const float* __restrict__ outv, const float* __restrict__ scale,
    const float* __restrict__ shift, const float* __restrict__ W2,
    const float* __restrict__ asw, const float* __restrict__ adw,
    __half* __restrict__ hh, float* __restrict__ a_s, float* __restrict__ a_d, int n) {
  __shared__ float w2s[C * C];
  if (threadIdx.x < C * C) w2s[threadIdx.x] = W2[threadIdx.x];
  __syncthreads();
  int i = blockIdx.x * 256 + threadIdx.x;
  if (i >= n) return;
  float hn[C];
  #pragma unroll
  for (int c = 0; c < C; ++c) hn[c] = outv[(size_t)i * C + c] * scale[c] + shift[c];
  float h2[C];
  #pragma unroll
  for (int j = 0; j < C; ++j) {
    float acc = 0.f;
    #pragma unroll
    for (int c = 0; c < C; ++c) acc += hn[c] * w2s[c * C + j];
    h2[j] = acc;
  }
  float hs = 0.f, hd = 0.f;
  #pragma unroll
  for (int j = 0; j < C; ++j) { hs += h2[j] * asw[j]; hd += h2[j] * adw[j]; }
  a_s[i] = hs; a_d[i] = hd;
  unsigned wbits[8];
  #pragma unroll
  for (int j = 0; j < 8; ++j) {
    __half2 hq = __floats2half2_rn(h2[2 * j], h2[2 * j + 1]);
    memcpy(&wbits[j], &hq, 4);
  }
  uint4* hp = (uint4*)(hh + (size_t)i * 16);
  hp[0] = make_uint4(wbits[0], wbits[1], wbits[2], wbits[3]);
  hp[1] = make_uint4(wbits[4], wbits[5], wbits[6], wbits[7]);
}

// ---------------- graph segment offsets ----------------
__global__ void k_gstart(const int* __restrict__ batch, int* __restrict__ gs,
                         int n, int B_) {
  int g = blockIdx.x * blockDim.x + threadIdx.x;
  if (g > B_) return;
  if (g == B_) { gs[B_] = n; return; }
  int lo = 0, hi = n;
  while (lo < hi) { int mid = (lo + hi) >> 1; if (batch[mid] < g) lo = mid + 1; else hi = mid; }
  gs[g] = lo;
}

__global__ __launch_bounds__(256) void k_xe(
    const float* __restrict__ outv, const int* __restrict__ gs,
    float* __restrict__ xe, int B_) {
  int wave = blockIdx.x * 4 + (threadIdx.x >> 6);
  if (wave >= B_) return;
  int lane = threadIdx.x & 63;
  int c = lane & 15, sub = lane >> 4;
  int base = gs[wave], end = gs[wave + 1];
  float s = 0.f;
  for (int n0 = base + sub; n0 < end; n0 += 4) s += outv[(size_t)n0 * C + c];
  s += __shfl_down(s, 32);
  s += __shfl_down(s, 16);
  if (lane < 16) xe[(size_t)wave * C + c] = s / fmaxf((float)(end - base), 1.f);
}

// ---------------- D2RL tail: BN/MLP stages only (z3 out, no spills) ----------------
__global__ __launch_bounds__(512) void k_tail_z3(
    const float* __restrict__ xe_in,
    const float* __restrict__ gL1, const float* __restrict__ bL1,
    const float* __restrict__ Wl1, const float* __restrict__ bl1,
    const float* __restrict__ gL2, const float* __restrict__ bL2,
    const float* __restrict__ Wl2, const float* __restrict__ bl2,
    const float* __restrict__ gL3, const float* __restrict__ bL3,
    const float* __restrict__ Wl3, const float* __restrict__ bl3,
    float* __restrict__ z3buf, int B_) {
  __shared__ float ssum[2 * C], ssq[2 * C], sc[2 * C], sh[2 * C];
  int t = threadIdx.x;
  float invB = 1.f / (float)B_;
  float xe[C];
  #pragma unroll
  for (int c = 0; c < C; ++c) xe[c] = xe_in[(size_t)t * C + c];

  if (t < 2 * C) { ssum[t] = 0.f; ssq[t] = 0.f; }
  __syncthreads();
  #pragma unroll
  for (int c = 0; c < C; ++c) {
    float s = xe[c], q = xe[c] * xe[c];
    for (int o = 32; o > 0; o >>= 1) { s += __shfl_down(s, o); q += __shfl_down(q, o); }
    if ((t & 63) == 0) { atomicAdd(&ssum[c], s); atomicAdd(&ssq[c], q); }
  }
  __syncthreads();
  if (t < C) {
    float mean = ssum[t] * invB, var = ssq[t] * invB - mean * mean;
    float s = gL1[t] * rsqrtf(var + 1e-5f);
    sc[t] = s; sh[t] = bL1[t] - mean * s;
  }
  __syncthreads();
  float z[C];
  #pragma unroll
  for (int j = 0; j < C; ++j) {
    float acc = bl1[j];
    #pragma unroll
    for (int c = 0; c < C; ++c) acc += (xe[c] * sc[c] + sh[c]) * Wl1[c * C + j];
    z[j] = fmaxf(acc, 0.f);
  }
  __syncthreads();

  if (t < 2 * C) { ssum[t] = 0.f; ssq[t] = 0.f; }
  __syncthreads();
  #pragma unroll
  for (int c = 0; c < C; ++c) {
    float s = z[c], q = z[c] * z[c];
    for (int o = 32; o > 0; o >>= 1) { s += __shfl_down(s, o); q += __shfl_down(q, o); }
    if ((t & 63) == 0) { atomicAdd(&ssum[c], s); atomicAdd(&ssq[c], q); }
    float s2 = xe[c], q2 = xe[c] * xe[c];
    for (int o = 32; o > 0; o >>= 1) { s2 += __shfl_down(s2, o); q2 += __shfl_down(q2, o); }
    if ((t & 63) == 0) { atomicAdd(&ssum[C + c], s2); atomicAdd(&ssq[C + c], q2); }
  }
  __syncthreads();
  if (t < 2 * C) {
    float mean = ssum[t] * invB, var = ssq[t] * invB - mean * mean;
    float s = gL2[t] * rsqrtf(var + 1e-5f);
    sc[t] = s; sh[t] = bL2[t] - mean * s;
  }
  __syncthreads();
  float z2[C];
  #pragma unroll
  for (int j = 0; j < C; ++j) {
    float acc = bl2[j];
    #pragma unroll
    for (int c = 0; c < C; ++c) acc += (z[c] * sc[c] + sh[c]) * Wl2[c * C + j];
    #pragma unroll
    for (int c = 0; c < C; ++c) acc += (xe[c] * sc[C + c] + sh[C + c]) * Wl2[(C + c) * C + j];
    z2[j] = fmaxf(acc, 0.f);
  }
  __syncthreads();

  if (t < 2 * C) { ssum[t] = 0.f; ssq[t] = 0.f; }
  __syncthreads();
  #pragma unroll
  for (int c = 0; c < C; ++c) {
    float s = z2[c], q = z2[c] * z2[c];
    for (int o = 32; o > 0; o >>= 1) { s += __shfl_down(s, o); q += __shfl_down(q, o); }
    if ((t & 63) == 0) { atomicAdd(&ssum[c], s); atomicAdd(&ssq[c], q); }
    float s2 = xe[c], q2 = xe[c] * xe[c];
    for (int o = 32; o > 0; o >>= 1) { s2 += __shfl_down(s2, o); q2 += __shfl_down(q2, o); }
    if ((t & 63) == 0) { atomicAdd(&ssum[C + c], s2); atomicAdd(&ssq[C + c], q2); }
  }
  __syncthreads();
  if (t < 2 * C) {
    float mean = ssum[t] * invB, var = ssq[t] * invB - mean * mean;
    float s = gL3[t] * rsqrtf(var + 1e-5f);
    sc[t] = s; sh[t] = bL3[t] - mean * s;
  }
  __syncthreads();
  #pragma unroll
  for (int j = 0; j < C; ++j) {
    float acc = bl3[j];
    #pragma unroll
    for (int c = 0; c < C; ++c) acc += (z2[c] * sc[c] + sh[c]) * Wl3[c * C + j];
    #pragma unroll
    for (int c = 0; c < C; ++c) acc += (xe[c] * sc[C + c] + sh[C + c]) * Wl3[(C + c) * C + j];
    z3buf[(size_t)t * C + j] = fmaxf(acc, 0.f);
  }
}

// ---------------- heads: one wave per graph, lane j = output j ----------------
__global__ __launch_bounds__(256) void k_heads(
    const float* __restrict__ z3buf,
    const float* __restrict__ Wx, const float* __restrict__ bx,
    const float* __restrict__ Wy, const float* __restrict__ by,
    const float* __restrict__ Wr, const float* __restrict__ br,
    float* __restrict__ out, int B_) {
  int wv = blockIdx.x * 4 + (threadIdx.x >> 6);
  if (wv >= B_) return;
  int lane = threadIdx.x & 63;
  float z[C];
  #pragma unroll
  for (int c = 0; c < C; ++c) z[c] = z3buf[(size_t)wv * C + c];

  // x head
  float ax = bx[lane];
  #pragma unroll
  for (int c = 0; c < C; ++c) ax += z[c] * Wx[c * 64 + lane];
  float m = ax;
  #pragma unroll
  for (int o = 32; o > 0; o >>= 1) m = fmaxf(m, __shfl_xor(m, o));
  float e = __expf(ax - m);
  float s = e;
  #pragma unroll
  for (int o = 32; o > 0; o >>= 1) s += __shfl_xor(s, o);
  out[(size_t)wv * 64 + lane] = e / s;

  // y head
  float ay = by[lane];
  #pragma unroll
  for (int c = 0; c < C; ++c) ay += z[c] * Wy[c * 64 + lane];
  m = ay;
  #pragma unroll
  for (int o = 32; o > 0; o >>= 1) m = fmaxf(m, __shfl_xor(m, o));
  e = __expf(ay - m);
  s = e;
  #pragma unroll
  for (int o = 32; o > 0; o >>= 1) s += __shfl_xor(s, o);
  out[(size_t)B_ * 64 + (size_t)wv * 64 + lane] = e / s;

  // rot head (4 outputs in lanes 0..3; shfl_xor 1,2 stays within the quad)
  if (lane < 4) {
    float ar = br[lane];
    #pragma unroll
    for (int c = 0; c < C; ++c) ar += z[c] * Wr[c * 4 + lane];
    float mr = ar;
    mr = fmaxf(mr, __shfl_xor(mr, 1));
    mr = fmaxf(mr, __shfl_xor(mr, 2));
    float er = __expf(ar - mr);
    float sr = er;
    sr += __shfl_xor(sr, 1);
    sr += __shfl_xor(sr, 2);
    out[(size_t)B_ * 128 + (size_t)wv * 4 + lane] = er / sr;
  }
}

extern "C" void kernel_launch(void* const* d_in, const int* in_sizes, int n_in,
                              void* d_out, int out_size, void* d_ws, size_t ws_size,
                              hipStream_t stream) {
  const float* x     = (const float*)d_in[0];
  const int*   eidx  = (const int*)d_in[1];
  const float* eattr = (const float*)d_in[2];
  const int*   batch = (const int*)d_in[3];
  const float* W1  = (const float*)d_in[4];
  const float* We1 = (const float*)d_in[5];
  const float* as1 = (const float*)d_in[6];
  const float* ad1 = (const float*)d_in[7];
  const float* ae1 = (const float*)d_in[8];
  const float* b1  = (const float*)d_in[9];
  const float* g1  = (const float*)d_in[10];
  const float* bb1 = (const float*)d_in[11];
  const float* W2  = (const float*)d_in[12];
  const float* We2 = (const float*)d_in[13];
  const float* as2 = (const float*)d_in[14];
  const float* ad2 = (const float*)d_in[15];
  const float* ae2 = (const float*)d_in[16];
  const float* b2  = (const float*)d_in[17];
  const float* gL1 = (const float*)d_in[18];
  const float* bL1 = (const float*)d_in[19];
  const float* Wl1 = (const float*)d_in[20];
  const float* bl1 = (const float*)d_in[21];
  const float* gL2 = (const float*)d_in[22];
  const float* bL2 = (const float*)d_in[23];
  const float* Wl2 = (const float*)d_in[24];
  const float* bl2 = (const float*)d_in[25];
  const float* gL3 = (const float*)d_in[26];
  const float* bL3 = (const float*)d_in[27];
  const float* Wl3 = (const float*)d_in[28];
  const float* bl3 = (const float*)d_in[29];
  const float* Wx  = (const float*)d_in[30];
  const float* bx  = (const float*)d_in[31];
  const float* Wy  = (const float*)d_in[32];
  const float* by  = (const float*)d_in[33];
  const float* Wr  = (const float*)d_in[34];
  const float* br  = (const float*)d_in[35];

  int N = in_sizes[3];
  int E = in_sizes[2] / 2;
  int B = out_size / 132;
  int nblk = (N + 511) / 512;

  char* w = (char*)d_ws;
  size_t o = 0;
  auto alloc = [&](size_t bytes) { char* p = w + o; o += (bytes + 15) & ~15ull; return p; };
  uint2*  bucket = (uint2*)alloc((size_t)E * 8);
  int*    rank   = (int*)alloc((size_t)E * 4);
  __half* hh     = (__half*)alloc((size_t)N * C * 2);
  float*  outv   = (float*)alloc((size_t)N * C * 4);
  float*  a_s    = (float*)alloc((size_t)N * 4);
  float*  a_d    = (float*)alloc((size_t)N * 4);
  int*    counts = (int*)alloc((size_t)N * 4);
  int*    offs   = (int*)alloc((size_t)(N + 4) * 4);
  int*    bsum   = (int*)alloc((size_t)(nblk + 4) * 4);
  float*  bn     = (float*)alloc(64 * 4);
  float*  xe     = (float*)alloc((size_t)B * C * 4);
  int*    gs     = (int*)alloc((size_t)(B + 4) * 4);
  float*  z3buf  = (float*)alloc((size_t)B * C * 4);

  const int* src = eidx;
  const int* dst = eidx + E;
  int ebl = (E + 255) / 256;
  int nbl = (N + 255) / 256;

  hipMemsetAsync(counts, 0, (size_t)N * 4, stream);
  hipMemsetAsync(bn, 0, 32 * 4, stream);

  k_gemm1<<<(N + 63) / 64, 256, 0, stream>>>(x, W1, as1, ad1, hh, a_s, a_d, N);
  k_hist_rank<<<ebl, 256, 0, stream>>>(dst, counts, rank, E);
  k_scan1<<<nblk, 512, 0, stream>>>(counts, bsum, N);
  k_scan2<<<1, 512, 0, stream>>>(bsum, offs, nblk, N);
  k_scan3<<<nblk, 512, 0, stream>>>(counts, bsum, offs, N);
  k_scatter<<<ebl, 256, 0, stream>>>(src, dst, (const float2*)eattr, offs, rank,
                                     We1, ae1, We2, ae2, bucket, E);
  k_gather<<<(N + 3) / 4, 256, 0, stream>>>(bucket, offs, a_s, a_d, hh, b1,
                                            outv, bn, bn + 16, 0, 1, N);
  k_bnp<<<1, 64, 0, stream>>>(bn, bn + 16, g1, bb1, bn + 32, bn + 48, 1.f / (float)N);
  k_node2<<<nbl, 256, 0, stream>>>(outv, bn + 32, bn + 48, W2, as2, ad2, hh, a_s, a_d, N);
  k_gather<<<(N + 3) / 4, 256, 0, stream>>>(bucket, offs, a_s, a_d, hh, b2,
                                            outv, bn, bn + 16, 1, 0, N);
  k_gstart<<<(B + 1 + 255) / 256, 256, 0, stream>>>(batch, gs, N, B);
  k_xe<<<(B + 3) / 4, 256, 0, stream>>>(outv, gs, xe, B);
  k_tail_z3<<<1, B, 0, stream>>>(xe, gL1, bL1, Wl1, bl1, gL2, bL2, Wl2, bl2,
                                 gL3, bL3, Wl3, bl3, z3buf, B);
  k_heads<<<(B + 3) / 4, 256, 0, stream>>>(z3buf, Wx, bx, Wy, by, Wr, br,
                                           (float*)d_out, B);
}

// Round 5
// 712.497 us; speedup vs baseline: 1.8612x; 1.8612x over previous
//
#include <hip/hip_runtime.h>
#include <hip/hip_fp16.h>
#include <math.h>

#define C 16
#define FIN 128

typedef unsigned int u32x2 __attribute__((ext_vector_type(2)));

// ---------------- GEMM x@W1 (100k x 128 x 16) + fused a_s/a_d ----------------
// h is stored as fp16 rows (32B); gather working set (3.2MB) fits per-XCD L2.
__global__ __launch_bounds__(256) void k_gemm1(
    const float* __restrict__ x, const float* __restrict__ W,
    const float* __restrict__ asw, const float* __restrict__ adw,
    __half* __restrict__ hh, float* __restrict__ a_s, float* __restrict__ a_d, int n) {
  __shared__ float xs[64 * 129];
  __shared__ float Ws[FIN * C];
  __shared__ float pAs[4][64], pAd[4][64];
  int t = threadIdx.x;
  int node0 = blockIdx.x * 64;
  for (int i = t; i < FIN * C; i += 256) Ws[i] = W[i];
  for (int i = t; i < 64 * FIN; i += 256) {
    int r = i >> 7, c = i & 127;
    int node = node0 + r;
    xs[r * 129 + c] = (node < n) ? x[(size_t)node * FIN + c] : 0.f;
  }
  __syncthreads();
  int nn = t & 63, cg = (t >> 6) * 4, grp = t >> 6;
  float a0 = 0.f, a1 = 0.f, a2 = 0.f, a3 = 0.f;
  const float* xr = &xs[nn * 129];
  #pragma unroll 8
  for (int k = 0; k < FIN; ++k) {
    float xv = xr[k];
    const float* wr = &Ws[k * C + cg];
    a0 += xv * wr[0]; a1 += xv * wr[1]; a2 += xv * wr[2]; a3 += xv * wr[3];
  }
  int node = node0 + nn;
  if (node < n) {
    __half2 p0 = __floats2half2_rn(a0, a1), p1 = __floats2half2_rn(a2, a3);
    unsigned u0, u1;
    memcpy(&u0, &p0, 4); memcpy(&u1, &p1, 4);
    *(uint2*)(hh + (size_t)node * 16 + cg) = make_uint2(u0, u1);
  }
  pAs[grp][nn] = a0 * asw[cg] + a1 * asw[cg + 1] + a2 * asw[cg + 2] + a3 * asw[cg + 3];
  pAd[grp][nn] = a0 * adw[cg] + a1 * adw[cg + 1] + a2 * adw[cg + 2] + a3 * adw[cg + 3];
  __syncthreads();
  if (t < 64 && node0 + t < n) {
    a_s[node0 + t] = pAs[0][t] + pAs[1][t] + pAs[2][t] + pAs[3][t];
    a_d[node0 + t] = pAd[0][t] + pAd[1][t] + pAd[2][t] + pAd[3][t];
  }
}

// ---------------- CSR build ----------------
__global__ __launch_bounds__(256) void k_hist_rank(
    const int* __restrict__ dst, int* __restrict__ counts,
    int* __restrict__ rank, int ne) {
  int e = blockIdx.x * 256 + threadIdx.x;
  if (e < ne) rank[e] = atomicAdd(&counts[dst[e]], 1);
}

__global__ __launch_bounds__(512) void k_scan1(const int* __restrict__ counts,
                                               int* __restrict__ bsum, int n) {
  __shared__ int sd[512];
  int i = blockIdx.x * 512 + threadIdx.x;
  sd[threadIdx.x] = (i < n) ? counts[i] : 0;
  __syncthreads();
  for (int s = 256; s > 0; s >>= 1) {
    if (threadIdx.x < s) sd[threadIdx.x] += sd[threadIdx.x + s];
    __syncthreads();
  }
  if (threadIdx.x == 0) bsum[blockIdx.x] = sd[0];
}

__global__ __launch_bounds__(512) void k_scan2(int* __restrict__ bsum,
                                               int* __restrict__ offs,
                                               int nblk, int n) {
  __shared__ int sd[512];
  int t = threadIdx.x;
  int v = (t < nblk) ? bsum[t] : 0;
  sd[t] = v;
  __syncthreads();
  for (int off = 1; off < 512; off <<= 1) {
    int x = (t >= off) ? sd[t - off] : 0;
    __syncthreads();
    sd[t] += x;
    __syncthreads();
  }
  if (t < nblk) bsum[t] = sd[t] - v;
  if (t == nblk - 1) offs[n] = sd[t];
}

__global__ __launch_bounds__(512) void k_scan3(const int* __restrict__ counts,
                                               const int* __restrict__ bsum,
                                               int* __restrict__ offs, int n) {
  __shared__ int sd[512];
  int t = threadIdx.x;
  int i = blockIdx.x * 512 + t;
  int v = (i < n) ? counts[i] : 0;
  sd[t] = v;
  __syncthreads();
  for (int off = 1; off < 512; off <<= 1) {
    int x = (t >= off) ? sd[t - off] : 0;
    __syncthreads();
    sd[t] += x;
    __syncthreads();
  }
  if (i < n) offs[i] = bsum[blockIdx.x] + sd[t] - v;
}

// Precompute per-edge attention scalars for BOTH layers: s_l = ea . we_l.
__global__ __launch_bounds__(256) void k_scatter(
    const int* __restrict__ src, const int* __restrict__ dst,
    const float2* __restrict__ ea, const int* __restrict__ offs,
    const int* __restrict__ rank,
    const float* __restrict__ We1, const float* __restrict__ ae1,
    const float* __restrict__ We2, const float* __restrict__ ae2,
    uint2* __restrict__ bucket, int ne) {
  int e = blockIdx.x * 256 + threadIdx.x;
  if (e >= ne) return;
  float w01 = 0.f, w11 = 0.f, w02 = 0.f, w12 = 0.f;
  #pragma unroll
  for (int c = 0; c < C; ++c) {
    w01 += We1[c] * ae1[c]; w11 += We1[C + c] * ae1[c];
    w02 += We2[c] * ae2[c]; w12 += We2[C + c] * ae2[c];
  }
  int d = dst[e];
  float2 a = ea[e];
  __half2 hp = __floats2half2_rn(a.x * w01 + a.y * w11, a.x * w02 + a.y * w12);
  unsigned hb;
  memcpy(&hb, &hp, 4);
  bucket[offs[d] + rank[e]] = make_uint2((unsigned)src[e], hb);
}

// ---------------- per-node gather: 8 lanes per node, 2 lanes per edge -------
// Empirical law from rounds 0-4: gather time ~ 190us x (waves / 25k),
// invariant to bytes, line-requests, and iteration count. So: pack MORE nodes
// per wave. 8 lanes/node -> 32 nodes/block -> 12.5k waves (half of the 192us
// configs). 4 edge-pairs per node, degree loop stride 4 (~8 iters, iterations
// shown free). Pair structure identical to the verified round-3 kernel.
__global__ __launch_bounds__(256) void k_gather(
    const uint2* __restrict__ bucket, const int* __restrict__ offs,
    const float* __restrict__ a_s, const float* __restrict__ a_d,
    const __half* __restrict__ hh, const float* __restrict__ bias,
    float* __restrict__ outv, float* __restrict__ bnsum, float* __restrict__ bnsq,
    int lay, int do_bn, int n) {
  __shared__ float sbn[32];
  int t = threadIdx.x;
  if (do_bn) {
    if (t < 32) sbn[t] = 0.f;
    __syncthreads();
  }

  int node = blockIdx.x * 32 + (t >> 3);
  int l = t & 7, f = l & 1, p = l >> 1;   // 4 pairs per node

  float acc[8];
  #pragma unroll
  for (int j = 0; j < 8; ++j) acc[j] = 0.f;
  float den = 0.f, ssum = 0.f;
  int o0 = 0, o1 = 0;
  float adi = 0.f, asi = 0.f;
  if (node < n) {
    o0 = offs[node]; o1 = offs[node + 1];
    adi = a_d[node]; asi = a_s[node];
    int e = o0 + p;
    u32x2 r = {0u, 0u};
    if (e < o1) r = __builtin_nontemporal_load((const u32x2*)(bucket + e));
    while (e < o1) {
      int en = e + 4;
      u32x2 rn = {0u, 0u};
      if (en < o1) rn = __builtin_nontemporal_load((const u32x2*)(bucket + en));
      int s = (int)r.x;
      unsigned scb = r.y;
      __half2 sc2;
      memcpy(&sc2, &scb, 4);
      float se = lay ? __high2float(sc2) : __low2float(sc2);
      float asv = a_s[s];
      uint4 hv = *(const uint4*)(hh + ((size_t)s << 4) + (f << 3));
      float lg = asv + adi + se;
      lg = lg > 0.f ? lg : 0.2f * lg;
      float ex = __expf(lg);
      den += ex; ssum += se;
      __half2 t0, t1, t2, t3;
      memcpy(&t0, &hv.x, 4); memcpy(&t1, &hv.y, 4);
      memcpy(&t2, &hv.z, 4); memcpy(&t3, &hv.w, 4);
      float2 g0 = __half22float2(t0), g1 = __half22float2(t1);
      float2 g2 = __half22float2(t2), g3 = __half22float2(t3);
      acc[0] += ex * g0.x; acc[1] += ex * g0.y;
      acc[2] += ex * g1.x; acc[3] += ex * g1.y;
      acc[4] += ex * g2.x; acc[5] += ex * g2.y;
      acc[6] += ex * g3.x; acc[7] += ex * g3.y;
      r = rn; e = en;
    }
  }
  // reduce over the 4 pairs (lane bits 1..2 of the 8-lane group); f-chains
  // stay separate; den/ssum are per-f duplicates (correct).
  #pragma unroll
  for (int off = 2; off <= 4; off <<= 1) {
    den += __shfl_xor(den, off);
    ssum += __shfl_xor(ssum, off);
    #pragma unroll
    for (int j = 0; j < 8; ++j) acc[j] += __shfl_xor(acc[j], off);
  }

  float v[8];
  #pragma unroll
  for (int j = 0; j < 8; ++j) v[j] = 0.f;
  if (node < n) {
    float dgc = fmaxf((float)(o1 - o0), 1.f);
    float lg = asi + adi + ssum / dgc;
    lg = lg > 0.f ? lg : 0.2f * lg;
    float exs = __expf(lg);
    uint4 hv = *(const uint4*)(hh + ((size_t)node << 4) + (f << 3));
    __half2 t0, t1, t2, t3;
    memcpy(&t0, &hv.x, 4); memcpy(&t1, &hv.y, 4);
    memcpy(&t2, &hv.z, 4); memcpy(&t3, &hv.w, 4);
    float2 g0 = __half22float2(t0), g1 = __half22float2(t1);
    float2 g2 = __half22float2(t2), g3 = __half22float2(t3);
    float hs[8] = {g0.x, g0.y, g1.x, g1.y, g2.x, g2.y, g3.x, g3.y};
    float inv = 1.f / (den + exs);
    const float* bp = bias + f * 8;
    #pragma unroll
    for (int j = 0; j < 8; ++j)
      v[j] = fmaxf((acc[j] + exs * hs[j]) * inv + bp[j], 0.f);
    if (p == 0) {
      float4* op = (float4*)(outv + ((size_t)node << 4));
      op[f * 2]     = make_float4(v[0], v[1], v[2], v[3]);
      op[f * 2 + 1] = make_float4(v[4], v[5], v[6], v[7]);
    }
  }

  if (do_bn) {
    float sv[8], qv[8];
    bool act = (node < n) && (p == 0);
    #pragma unroll
    for (int j = 0; j < 8; ++j) {
      sv[j] = act ? v[j] : 0.f;
      qv[j] = sv[j] * sv[j];
    }
    // fold the 8 node-groups of this wave (p==0 lanes live at l in {0,1} of
    // each 8-lane group: global lanes 0,1,8,9,...,56,57)
    #pragma unroll
    for (int j = 0; j < 8; ++j) {
      sv[j] += __shfl_down(sv[j], 8);  qv[j] += __shfl_down(qv[j], 8);
      sv[j] += __shfl_down(sv[j], 16); qv[j] += __shfl_down(qv[j], 16);
      sv[j] += __shfl_down(sv[j], 32); qv[j] += __shfl_down(qv[j], 32);
    }
    if ((t & 63) < 2) {
      #pragma unroll
      for (int j = 0; j < 8; ++j) {
        atomicAdd(&sbn[f * 8 + j], sv[j]);
        atomicAdd(&sbn[16 + f * 8 + j], qv[j]);
      }
    }
    __syncthreads();
    if (t < 16) atomicAdd(&bnsum[t], sbn[t]);
    else if (t < 32) atomicAdd(&bnsq[t - 16], sbn[t]);
  }
}

__global__ void k_bnp(const float* __restrict__ bnsum, const float* __restrict__ bnsq,
                      const float* __restrict__ g, const float* __restrict__ bb,
                      float* __restrict__ scale, float* __restrict__ shift, float invn) {
  int c = threadIdx.x;
  if (c >= C) return;
  float mean = bnsum[c] * invn;
  float var = bnsq[c] * invn - mean * mean;
  float s = g[c] * rsqrtf(var + 1e-5f);
  scale[c] = s; shift[c] = bb[c] - mean * s;
}

// ---------------- BN + 16x16 matmul + a_s/a_d for layer 2 ----------------
__global__ __launch_bounds__(256) void k_node2(
    const float* __restrict__ outv, const float* __restrict__ scale,
    const float* __restrict__ shift, const float* __restrict__ W2,
    const float* __restrict__ asw, const float* __restrict__ adw,
    __half* __restrict__ hh, float* __restrict__ a_s, float* __restrict__ a_d, int n) {
  __shared__ float w2s[C * C];
  if (threadIdx.x < C * C) w2s[threadIdx.x] = W2[threadIdx.x];
  __syncthreads();
  int i = blockIdx.x * 256 + threadIdx.x;
  if (i >= n) return;
  float hn[C];
  #pragma unroll
  for (int c = 0; c < C; ++c) hn[c] = outv[(size_t)i * C + c] * scale[c] + shift[c];
  float h2[C];
  #pragma unroll
  for (int j = 0; j < C; ++j) {
    float acc = 0.f;
    #pragma unroll
    for (int c = 0; c < C; ++c) acc += hn[c] * w2s[c * C + j];
    h2[j] = acc;
  }
  float hs = 0.f, hd = 0.f;
  #pragma unroll
  for (int j = 0; j < C; ++j) { hs += h2[j] * asw[j]; hd += h2[j] * adw[j]; }
  a_s[i] = hs; a_d[i] = hd;
  unsigned wbits[8];
  #pragma unroll
  for (int j = 0; j < 8; ++j) {
    __half2 hq = __floats2half2_rn(h2[2 * j], h2[2 * j + 1]);
    memcpy(&wbits[j], &hq, 4);
  }
  uint4* hp = (uint4*)(hh + (size_t)i * 16);
  hp[0] = make_uint4(wbits[0], wbits[1], wbits[2], wbits[3]);
  hp[1] = make_uint4(wbits[4], wbits[5], wbits[6], wbits[7]);
}

// ---------------- graph segment offsets ----------------
__global__ void k_gstart(const int* __restrict__ batch, int* __restrict__ gs,
                         int n, int B_) {
  int g = blockIdx.x * blockDim.x + threadIdx.x;
  if (g > B_) return;
  if (g == B_) { gs[B_] = n; return; }
  int lo = 0, hi = n;
  while (lo < hi) { int mid = (lo + hi) >> 1; if (batch[mid] < g) lo = mid + 1; else hi = mid; }
  gs[g] = lo;
}

__global__ __launch_bounds__(256) void k_xe(
    const float* __restrict__ outv, const int* __restrict__ gs,
    float* __restrict__ xe, int B_) {
  int wave = blockIdx.x * 4 + (threadIdx.x >> 6);
  if (wave >= B_) return;
  int lane = threadIdx.x & 63;
  int c = lane & 15, sub = lane >> 4;
  int base = gs[wave], end = gs[wave + 1];
  float s = 0.f;
  for (int n0 = base + sub; n0 < end; n0 += 4) s += outv[(size_t)n0 * C + c];
  s += __shfl_down(s, 32);
  s += __shfl_down(s, 16);
  if (lane < 16) xe[(size_t)wave * C + c] = s / fmaxf((float)(end - base), 1.f);
}

// ---------------- D2RL tail: BN/MLP stages only (z3 out, no spills) ----------------
__global__ __launch_bounds__(512) void k_tail_z3(
    const float* __restrict__ xe_in,
    const float* __restrict__ gL1, const float* __restrict__ bL1,
    const float* __restrict__ Wl1, const float* __restrict__ bl1,
    const float* __restrict__ gL2, const float* __restrict__ bL2,
    const float* __restrict__ Wl2, const float* __restrict__ bl2,
    const float* __restrict__ gL3, const float* __restrict__ bL3,
    const float* __restrict__ Wl3, const float* __restrict__ bl3,
    float* __restrict__ z3buf, int B_) {
  __shared__ float ssum[2 * C], ssq[2 * C], sc[2 * C], sh[2 * C];
  int t = threadIdx.x;
  float invB = 1.f / (float)B_;
  float xe[C];
  #pragma unroll
  for (int c = 0; c < C; ++c) xe[c] = xe_in[(size_t)t * C + c];

  if (t < 2 * C) { ssum[t] = 0.f; ssq[t] = 0.f; }
  __syncthreads();
  #pragma unroll
  for (int c = 0; c < C; ++c) {
    float s = xe[c], q = xe[c] * xe[c];
    for (int o = 32; o > 0; o >>= 1) { s += __shfl_down(s, o); q += __shfl_down(q, o); }
    if ((t & 63) == 0) { atomicAdd(&ssum[c], s); atomicAdd(&ssq[c], q); }
  }
  __syncthreads();
  if (t < C) {
    float mean = ssum[t] * invB, var = ssq[t] * invB - mean * mean;
    float s = gL1[t] * rsqrtf(var + 1e-5f);
    sc[t] = s; sh[t] = bL1[t] - mean * s;
  }
  __syncthreads();
  float z[C];
  #pragma unroll
  for (int j = 0; j < C; ++j) {
    float acc = bl1[j];
    #pragma unroll
    for (int c = 0; c < C; ++c) acc += (xe[c] * sc[c] + sh[c]) * Wl1[c * C + j];
    z[j] = fmaxf(acc, 0.f);
  }
  __syncthreads();

  if (t < 2 * C) { ssum[t] = 0.f; ssq[t] = 0.f; }
  __syncthreads();
  #pragma unroll
  for (int c = 0; c < C; ++c) {
    float s = z[c], q = z[c] * z[c];
    for (int o = 32; o > 0; o >>= 1) { s += __shfl_down(s, o); q += __shfl_down(q, o); }
    if ((t & 63) == 0) { atomicAdd(&ssum[c], s); atomicAdd(&ssq[c], q); }
    float s2 = xe[c], q2 = xe[c] * xe[c];
    for (int o = 32; o > 0; o >>= 1) { s2 += __shfl_down(s2, o); q2 += __shfl_down(q2, o); }
    if ((t & 63) == 0) { atomicAdd(&ssum[C + c], s2); atomicAdd(&ssq[C + c], q2); }
  }
  __syncthreads();
  if (t < 2 * C) {
    float mean = ssum[t] * invB, var = ssq[t] * invB - mean * mean;
    float s = gL2[t] * rsqrtf(var + 1e-5f);
    sc[t] = s; sh[t] = bL2[t] - mean * s;
  }
  __syncthreads();
  float z2[C];
  #pragma unroll
  for (int j = 0; j < C; ++j) {
    float acc = bl2[j];
    #pragma unroll
    for (int c = 0; c < C; ++c) acc += (z[c] * sc[c] + sh[c]) * Wl2[c * C + j];
    #pragma unroll
    for (int c = 0; c < C; ++c) acc += (xe[c] * sc[C + c] + sh[C + c]) * Wl2[(C + c) * C + j];
    z2[j] = fmaxf(acc, 0.f);
  }
  __syncthreads();

  if (t < 2 * C) { ssum[t] = 0.f; ssq[t] = 0.f; }
  __syncthreads();
  #pragma unroll
  for (int c = 0; c < C; ++c) {
    float s = z2[c], q = z2[c] * z2[c];
    for (int o = 32; o > 0; o >>= 1) { s += __shfl_down(s, o); q += __shfl_down(q, o); }
    if ((t & 63) == 0) { atomicAdd(&ssum[c], s); atomicAdd(&ssq[c], q); }
    float s2 = xe[c], q2 = xe[c] * xe[c];
    for (int o = 32; o > 0; o >>= 1) { s2 += __shfl_down(s2, o); q2 += __shfl_down(q2, o); }
    if ((t & 63) == 0) { atomicAdd(&ssum[C + c], s2); atomicAdd(&ssq[C + c], q2); }
  }
  __syncthreads();
  if (t < 2 * C) {
    float mean = ssum[t] * invB, var = ssq[t] * invB - mean * mean;
    float s = gL3[t] * rsqrtf(var + 1e-5f);
    sc[t] = s; sh[t] = bL3[t] - mean * s;
  }
  __syncthreads();
  #pragma unroll
  for (int j = 0; j < C; ++j) {
    float acc = bl3[j];
    #pragma unroll
    for (int c = 0; c < C; ++c) acc += (z2[c] * sc[c] + sh[c]) * Wl3[c * C + j];
    #pragma unroll
    for (int c = 0; c < C; ++c) acc += (xe[c] * sc[C + c] + sh[C + c]) * Wl3[(C + c) * C + j];
    z3buf[(size_t)t * C + j] = fmaxf(acc, 0.f);
  }
}

// ---------------- heads: one wave per graph, lane j = output j ----------------
__global__ __launch_bounds__(256) void k_heads(
    const float* __restrict__ z3buf,
    const float* __restrict__ Wx, const float* __restrict__ bx,
    const float* __restrict__ Wy, const float* __restrict__ by,
    const float* __restrict__ Wr, const float* __restrict__ br,
    float* __restrict__ out, int B_) {
  int wv = blockIdx.x * 4 + (threadIdx.x >> 6);
  if (wv >= B_) return;
  int lane = threadIdx.x & 63;
  float z[C];
  #pragma unroll
  for (int c = 0; c < C; ++c) z[c] = z3buf[(size_t)wv * C + c];

  // x head
  float ax = bx[lane];
  #pragma unroll
  for (int c = 0; c < C; ++c) ax += z[c] * Wx[c * 64 + lane];
  float m = ax;
  #pragma unroll
  for (int o = 32; o > 0; o >>= 1) m = fmaxf(m, __shfl_xor(m, o));
  float e = __expf(ax - m);
  float s = e;
  #pragma unroll
  for (int o = 32; o > 0; o >>= 1) s += __shfl_xor(s, o);
  out[(size_t)wv * 64 + lane] = e / s;

  // y head
  float ay = by[lane];
  #pragma unroll
  for (int c = 0; c < C; ++c) ay += z[c] * Wy[c * 64 + lane];
  m = ay;
  #pragma unroll
  for (int o = 32; o > 0; o >>= 1) m = fmaxf(m, __shfl_xor(m, o));
  e = __expf(ay - m);
  s = e;
  #pragma unroll
  for (int o = 32; o > 0; o >>= 1) s += __shfl_xor(s, o);
  out[(size_t)B_ * 64 + (size_t)wv * 64 + lane] = e / s;

  // rot head (4 outputs in lanes 0..3; shfl_xor 1,2 stays within the quad)
  if (lane < 4) {
    float ar = br[lane];
    #pragma unroll
    for (int c = 0; c < C; ++c) ar += z[c] * Wr[c * 4 + lane];
    float mr = ar;
    mr = fmaxf(mr, __shfl_xor(mr, 1));
    mr = fmaxf(mr, __shfl_xor(mr, 2));
    float er = __expf(ar - mr);
    float sr = er;
    sr += __shfl_xor(sr, 1);
    sr += __shfl_xor(sr, 2);
    out[(size_t)B_ * 128 + (size_t)wv * 4 + lane] = er / sr;
  }
}

extern "C" void kernel_launch(void* const* d_in, const int* in_sizes, int n_in,
                              void* d_out, int out_size, void* d_ws, size_t ws_size,
                              hipStream_t stream) {
  const float* x     = (const float*)d_in[0];
  const int*   eidx  = (const int*)d_in[1];
  const float* eattr = (const float*)d_in[2];
  const int*   batch = (const int*)d_in[3];
  const float* W1  = (const float*)d_in[4];
  const float* We1 = (const float*)d_in[5];
  const float* as1 = (const float*)d_in[6];
  const float* ad1 = (const float*)d_in[7];
  const float* ae1 = (const float*)d_in[8];
  const float* b1  = (const float*)d_in[9];
  const float* g1  = (const float*)d_in[10];
  const float* bb1 = (const float*)d_in[11];
  const float* W2  = (const float*)d_in[12];
  const float* We2 = (const float*)d_in[13];
  const float* as2 = (const float*)d_in[14];
  const float* ad2 = (const float*)d_in[15];
  const float* ae2 = (const float*)d_in[16];
  const float* b2  = (const float*)d_in[17];
  const float* gL1 = (const float*)d_in[18];
  const float* bL1 = (const float*)d_in[19];
  const float* Wl1 = (const float*)d_in[20];
  const float* bl1 = (const float*)d_in[21];
  const float* gL2 = (const float*)d_in[22];
  const float* bL2 = (const float*)d_in[23];
  const float* Wl2 = (const float*)d_in[24];
  const float* bl2 = (const float*)d_in[25];
  const float* gL3 = (const float*)d_in[26];
  const float* bL3 = (const float*)d_in[27];
  const float* Wl3 = (const float*)d_in[28];
  const float* bl3 = (const float*)d_in[29];
  const float* Wx  = (const float*)d_in[30];
  const float* bx  = (const float*)d_in[31];
  const float* Wy  = (const float*)d_in[32];
  const float* by  = (const float*)d_in[33];
  const float* Wr  = (const float*)d_in[34];
  const float* br  = (const float*)d_in[35];

  int N = in_sizes[3];
  int E = in_sizes[2] / 2;
  int B = out_size / 132;
  int nblk = (N + 511) / 512;

  char* w = (char*)d_ws;
  size_t o = 0;
  auto alloc = [&](size_t bytes) { char* p = w + o; o += (bytes + 15) & ~15ull; return p; };
  uint2*  bucket = (uint2*)alloc((size_t)E * 8);
  int*    rank   = (int*)alloc((size_t)E * 4);
  __half* hh     = (__half*)alloc((size_t)N * C * 2);
  float*  outv   = (float*)alloc((size_t)N * C * 4);
  float*  a_s    = (float*)alloc((size_t)N * 4);
  float*  a_d    = (float*)alloc((size_t)N * 4);
  int*    counts = (int*)alloc((size_t)N * 4);
  int*    offs   = (int*)alloc((size_t)(N + 4) * 4);
  int*    bsum   = (int*)alloc((size_t)(nblk + 4) * 4);
  float*  bn     = (float*)alloc(64 * 4);
  float*  xe     = (float*)alloc((size_t)B * C * 4);
  int*    gs     = (int*)alloc((size_t)(B + 4) * 4);
  float*  z3buf  = (float*)alloc((size_t)B * C * 4);

  const int* src = eidx;
  const int* dst = eidx + E;
  int ebl = (E + 255) / 256;
  int nbl = (N + 255) / 256;

  hipMemsetAsync(counts, 0, (size_t)N * 4, stream);
  hipMemsetAsync(bn, 0, 32 * 4, stream);

  k_gemm1<<<(N + 63) / 64, 256, 0, stream>>>(x, W1, as1, ad1, hh, a_s, a_d, N);
  k_hist_rank<<<ebl, 256, 0, stream>>>(dst, counts, rank, E);
  k_scan1<<<nblk, 512, 0, stream>>>(counts, bsum, N);
  k_scan2<<<1, 512, 0, stream>>>(bsum, offs, nblk, N);
  k_scan3<<<nblk, 512, 0, stream>>>(counts, bsum, offs, N);
  k_scatter<<<ebl, 256, 0, stream>>>(src, dst, (const float2*)eattr, offs, rank,
                                     We1, ae1, We2, ae2, bucket, E);
  k_gather<<<(N + 31) / 32, 256, 0, stream>>>(bucket, offs, a_s, a_d, hh, b1,
                                              outv, bn, bn + 16, 0, 1, N);
  k_bnp<<<1, 64, 0, stream>>>(bn, bn + 16, g1, bb1, bn + 32, bn + 48, 1.f / (float)N);
  k_node2<<<nbl, 256, 0, stream>>>(outv, bn + 32, bn + 48, W2, as2, ad2, hh, a_s, a_d, N);
  k_gather<<<(N + 31) / 32, 256, 0, stream>>>(bucket, offs, a_s, a_d, hh, b2,
                                              outv, bn, bn + 16, 1, 0, N);
  k_gstart<<<(B + 1 + 255) / 256, 256, 0, stream>>>(batch, gs, N, B);
  k_xe<<<(B + 3) / 4, 256, 0, stream>>>(outv, gs, xe, B);
  k_tail_z3<<<1, B, 0, stream>>>(xe, gL1, bL1, Wl1, bl1, gL2, bL2, Wl2, bl2,
                                 gL3, bL3, Wl3, bl3, z3buf, B);
  k_heads<<<(B + 3) / 4, 256, 0, stream>>>(z3buf, Wx, bx, Wy, by, Wr, br,
                                           (float*)d_out, B);
}

// Round 6
// 672.829 us; speedup vs baseline: 1.9709x; 1.0590x over previous
//
#include <hip/hip_runtime.h>
#include <hip/hip_fp16.h>
#include <math.h>

#define C 16
#define FIN 128

typedef unsigned int u32x2 __attribute__((ext_vector_type(2)));

// ---------------- GEMM x@W1 (100k x 128 x 16) + fused a_s/a_d ----------------
__global__ __launch_bounds__(256) void k_gemm1(
    const float* __restrict__ x, const float* __restrict__ W,
    const float* __restrict__ asw, const float* __restrict__ adw,
    __half* __restrict__ hh, float* __restrict__ a_s, float* __restrict__ a_d, int n) {
  __shared__ float xs[64 * 129];
  __shared__ float Ws[FIN * C];
  __shared__ float pAs[4][64], pAd[4][64];
  int t = threadIdx.x;
  int node0 = blockIdx.x * 64;
  for (int i = t; i < FIN * C; i += 256) Ws[i] = W[i];
  for (int i = t; i < 64 * FIN; i += 256) {
    int r = i >> 7, c = i & 127;
    int node = node0 + r;
    xs[r * 129 + c] = (node < n) ? x[(size_t)node * FIN + c] : 0.f;
  }
  __syncthreads();
  int nn = t & 63, cg = (t >> 6) * 4, grp = t >> 6;
  float a0 = 0.f, a1 = 0.f, a2 = 0.f, a3 = 0.f;
  const float* xr = &xs[nn * 129];
  #pragma unroll 8
  for (int k = 0; k < FIN; ++k) {
    float xv = xr[k];
    const float* wr = &Ws[k * C + cg];
    a0 += xv * wr[0]; a1 += xv * wr[1]; a2 += xv * wr[2]; a3 += xv * wr[3];
  }
  int node = node0 + nn;
  if (node < n) {
    __half2 p0 = __floats2half2_rn(a0, a1), p1 = __floats2half2_rn(a2, a3);
    unsigned u0, u1;
    memcpy(&u0, &p0, 4); memcpy(&u1, &p1, 4);
    *(uint2*)(hh + (size_t)node * 16 + cg) = make_uint2(u0, u1);
  }
  pAs[grp][nn] = a0 * asw[cg] + a1 * asw[cg + 1] + a2 * asw[cg + 2] + a3 * asw[cg + 3];
  pAd[grp][nn] = a0 * adw[cg] + a1 * adw[cg + 1] + a2 * adw[cg + 2] + a3 * adw[cg + 3];
  __syncthreads();
  if (t < 64 && node0 + t < n) {
    a_s[node0 + t] = pAs[0][t] + pAs[1][t] + pAs[2][t] + pAs[3][t];
    a_d[node0 + t] = pAd[0][t] + pAd[1][t] + pAd[2][t] + pAd[3][t];
  }
}

// ---------------- generic scan kernels (used for bin table / fallback) ------
__global__ __launch_bounds__(512) void k_scan1(const int* __restrict__ counts,
                                               int* __restrict__ bsum, int n) {
  __shared__ int sd[512];
  int i = blockIdx.x * 512 + threadIdx.x;
  sd[threadIdx.x] = (i < n) ? counts[i] : 0;
  __syncthreads();
  for (int s = 256; s > 0; s >>= 1) {
    if (threadIdx.x < s) sd[threadIdx.x] += sd[threadIdx.x + s];
    __syncthreads();
  }
  if (threadIdx.x == 0) bsum[blockIdx.x] = sd[0];
}

__global__ __launch_bounds__(512) void k_scan2(int* __restrict__ bsum,
                                               int* __restrict__ offs,
                                               int nblk, int n) {
  __shared__ int sd[512];
  int t = threadIdx.x;
  int v = (t < nblk) ? bsum[t] : 0;
  sd[t] = v;
  __syncthreads();
  for (int off = 1; off < 512; off <<= 1) {
    int x = (t >= off) ? sd[t - off] : 0;
    __syncthreads();
    sd[t] += x;
    __syncthreads();
  }
  if (t < nblk) bsum[t] = sd[t] - v;
  if (t == nblk - 1) offs[n] = sd[t];
}

__global__ __launch_bounds__(512) void k_scan3(const int* __restrict__ counts,
                                               const int* __restrict__ bsum,
                                               int* __restrict__ offs, int n) {
  __shared__ int sd[512];
  int t = threadIdx.x;
  int i = blockIdx.x * 512 + t;
  int v = (i < n) ? counts[i] : 0;
  sd[t] = v;
  __syncthreads();
  for (int off = 1; off < 512; off <<= 1) {
    int x = (t >= off) ? sd[t - off] : 0;
    __syncthreads();
    sd[t] += x;
    __syncthreads();
  }
  if (i < n) offs[i] = bsum[blockIdx.x] + sd[t] - v;
}

// ---------------- ATOMIC-FREE CSR: MSD 2-level counting sort ----------------
// Device atomics on gfx950 write through to HBM (~32B each: round-5 PMC showed
// 112MB WRITE_SIZE for 3.2M atomics) -> 129us floor. This path uses only LDS
// atomics. p1 partitions edges by coarse bin (dst>>8, <=512 bins); p2 (one
// block per coarse bin) sorts by fine bin (dst&255) = exact node, writes offs
// and the final bucket. No stability needed: within-node order is commutative.

__global__ __launch_bounds__(256) void k_p1count(
    const int* __restrict__ dst, int* __restrict__ histT,
    int ne, int chunk, int G, int nbin) {
  __shared__ int hist[512];
  int g = blockIdx.x, t = threadIdx.x;
  for (int i = t; i < nbin; i += 256) hist[i] = 0;
  __syncthreads();
  int e0 = g * chunk, e1 = e0 + chunk; if (e1 > ne) e1 = ne;
  for (int e = e0 + t; e < e1; e += 256) atomicAdd(&hist[dst[e] >> 8], 1);
  __syncthreads();
  for (int i = t; i < nbin; i += 256) histT[i * G + g] = hist[i];
}

__global__ __launch_bounds__(256) void k_p1scat(
    const int* __restrict__ src, const int* __restrict__ dst,
    const float2* __restrict__ ea, const int* __restrict__ histS,
    const float* __restrict__ We1, const float* __restrict__ ae1,
    const float* __restrict__ We2, const float* __restrict__ ae2,
    uint2* __restrict__ tmpR, int* __restrict__ tmpD,
    int ne, int chunk, int G, int nbin) {
  __shared__ int cur[512];
  int g = blockIdx.x, t = threadIdx.x;
  for (int i = t; i < nbin; i += 256) cur[i] = histS[i * G + g];
  float w01 = 0.f, w11 = 0.f, w02 = 0.f, w12 = 0.f;
  #pragma unroll
  for (int c = 0; c < C; ++c) {
    w01 += We1[c] * ae1[c]; w11 += We1[C + c] * ae1[c];
    w02 += We2[c] * ae2[c]; w12 += We2[C + c] * ae2[c];
  }
  __syncthreads();
  int e0 = g * chunk, e1 = e0 + chunk; if (e1 > ne) e1 = ne;
  for (int e = e0 + t; e < e1; e += 256) {
    int d = dst[e];
    int pos = atomicAdd(&cur[d >> 8], 1);   // LDS atomic
    float2 a = ea[e];
    __half2 hp = __floats2half2_rn(a.x * w01 + a.y * w11, a.x * w02 + a.y * w12);
    unsigned hb;
    memcpy(&hb, &hp, 4);
    tmpR[pos] = make_uint2((unsigned)src[e], hb);
    tmpD[pos] = d;
  }
}

__global__ __launch_bounds__(256) void k_p2(
    const uint2* __restrict__ tmpR, const int* __restrict__ tmpD,
    const int* __restrict__ histS,
    uint2* __restrict__ bucket, int* __restrict__ offs,
    int G, int nbin, int n, int ne) {
  __shared__ int hist[256], scn[256], cur[256];
  int b = blockIdx.x, t = threadIdx.x;
  int cs0 = histS[b * G];
  int cs1 = (b + 1 < nbin) ? histS[(b + 1) * G] : ne;
  hist[t] = 0;
  __syncthreads();
  for (int i = cs0 + t; i < cs1; i += 256) atomicAdd(&hist[tmpD[i] & 255], 1);
  __syncthreads();
  int v = hist[t];
  scn[t] = v;
  __syncthreads();
  for (int off = 1; off < 256; off <<= 1) {
    int x = (t >= off) ? scn[t - off] : 0;
    __syncthreads();
    scn[t] += x;
    __syncthreads();
  }
  int excl = scn[t] - v;
  int node = b * 256 + t;
  if (node <= n) offs[node] = cs0 + excl;   // node==n lands here too (=ne)
  if (b == 0 && t == 0) offs[n] = ne;       // cover n%256==0 corner (same value)
  cur[t] = cs0 + excl;
  __syncthreads();
  for (int i = cs0 + t; i < cs1; i += 256) {
    int d = tmpD[i];
    int pos = atomicAdd(&cur[d & 255], 1);  // LDS atomic
    bucket[pos] = tmpR[i];
  }
}

// ---------------- FALLBACK CSR (round-5 atomic path) ----------------
__global__ __launch_bounds__(256) void k_hist_rank(
    const int* __restrict__ dst, int* __restrict__ counts,
    int* __restrict__ rank, int ne) {
  int e = blockIdx.x * 256 + threadIdx.x;
  if (e < ne) rank[e] = atomicAdd(&counts[dst[e]], 1);
}

__global__ __launch_bounds__(256) void k_scatter(
    const int* __restrict__ src, const int* __restrict__ dst,
    const float2* __restrict__ ea, const int* __restrict__ offs,
    const int* __restrict__ rank,
    const float* __restrict__ We1, const float* __restrict__ ae1,
    const float* __restrict__ We2, const float* __restrict__ ae2,
    uint2* __restrict__ bucket, int ne) {
  int e = blockIdx.x * 256 + threadIdx.x;
  if (e >= ne) return;
  float w01 = 0.f, w11 = 0.f, w02 = 0.f, w12 = 0.f;
  #pragma unroll
  for (int c = 0; c < C; ++c) {
    w01 += We1[c] * ae1[c]; w11 += We1[C + c] * ae1[c];
    w02 += We2[c] * ae2[c]; w12 += We2[C + c] * ae2[c];
  }
  int d = dst[e];
  float2 a = ea[e];
  __half2 hp = __floats2half2_rn(a.x * w01 + a.y * w11, a.x * w02 + a.y * w12);
  unsigned hb;
  memcpy(&hb, &hp, 4);
  bucket[offs[d] + rank[e]] = make_uint2((unsigned)src[e], hb);
}

// ---------------- per-node gather: 4 lanes per node, 2 lanes per edge -------
// Empirical law (r0-r5): gather time ~ waves/25k x 190us, invariant to bytes,
// line-requests, iteration count. 4 lanes/node -> 64 nodes/block -> 6.25k
// waves. 2 edge-pairs per node, stride 2 (~16 iters). Pair structure as r3/r5.
__global__ __launch_bounds__(256) void k_gather(
    const uint2* __restrict__ bucket, const int* __restrict__ offs,
    const float* __restrict__ a_s, const float* __restrict__ a_d,
    const __half* __restrict__ hh, const float* __restrict__ bias,
    float* __restrict__ outv, float* __restrict__ bnsum, float* __restrict__ bnsq,
    int lay, int do_bn, int n) {
  __shared__ float sbn[32];
  int t = threadIdx.x;
  if (do_bn) {
    if (t < 32) sbn[t] = 0.f;
    __syncthreads();
  }

  int node = blockIdx.x * 64 + (t >> 2);
  int l = t & 3, f = l & 1, p = l >> 1;   // 2 pairs per node

  float acc[8];
  #pragma unroll
  for (int j = 0; j < 8; ++j) acc[j] = 0.f;
  float den = 0.f, ssum = 0.f;
  int o0 = 0, o1 = 0;
  float adi = 0.f, asi = 0.f;
  if (node < n) {
    o0 = offs[node]; o1 = offs[node + 1];
    adi = a_d[node]; asi = a_s[node];
    int e = o0 + p;
    u32x2 r = {0u, 0u};
    if (e < o1) r = __builtin_nontemporal_load((const u32x2*)(bucket + e));
    while (e < o1) {
      int en = e + 2;
      u32x2 rn = {0u, 0u};
      if (en < o1) rn = __builtin_nontemporal_load((const u32x2*)(bucket + en));
      int s = (int)r.x;
      unsigned scb = r.y;
      __half2 sc2;
      memcpy(&sc2, &scb, 4);
      float se = lay ? __high2float(sc2) : __low2float(sc2);
      float asv = a_s[s];
      uint4 hv = *(const uint4*)(hh + ((size_t)s << 4) + (f << 3));
      float lg = asv + adi + se;
      lg = lg > 0.f ? lg : 0.2f * lg;
      float ex = __expf(lg);
      den += ex; ssum += se;
      __half2 t0, t1, t2, t3;
      memcpy(&t0, &hv.x, 4); memcpy(&t1, &hv.y, 4);
      memcpy(&t2, &hv.z, 4); memcpy(&t3, &hv.w, 4);
      float2 g0 = __half22float2(t0), g1 = __half22float2(t1);
      float2 g2 = __half22float2(t2), g3 = __half22float2(t3);
      acc[0] += ex * g0.x; acc[1] += ex * g0.y;
      acc[2] += ex * g1.x; acc[3] += ex * g1.y;
      acc[4] += ex * g2.x; acc[5] += ex * g2.y;
      acc[6] += ex * g3.x; acc[7] += ex * g3.y;
      r = rn; e = en;
    }
  }
  // reduce over the 2 pairs (lane bit 1); f-chains stay separate.
  den += __shfl_xor(den, 2);
  ssum += __shfl_xor(ssum, 2);
  #pragma unroll
  for (int j = 0; j < 8; ++j) acc[j] += __shfl_xor(acc[j], 2);

  float v[8];
  #pragma unroll
  for (int j = 0; j < 8; ++j) v[j] = 0.f;
  if (node < n) {
    float dgc = fmaxf((float)(o1 - o0), 1.f);
    float lg = asi + adi + ssum / dgc;
    lg = lg > 0.f ? lg : 0.2f * lg;
    float exs = __expf(lg);
    uint4 hv = *(const uint4*)(hh + ((size_t)node << 4) + (f << 3));
    __half2 t0, t1, t2, t3;
    memcpy(&t0, &hv.x, 4); memcpy(&t1, &hv.y, 4);
    memcpy(&t2, &hv.z, 4); memcpy(&t3, &hv.w, 4);
    float2 g0 = __half22float2(t0), g1 = __half22float2(t1);
    float2 g2 = __half22float2(t2), g3 = __half22float2(t3);
    float hs[8] = {g0.x, g0.y, g1.x, g1.y, g2.x, g2.y, g3.x, g3.y};
    float inv = 1.f / (den + exs);
    const float* bp = bias + f * 8;
    #pragma unroll
    for (int j = 0; j < 8; ++j)
      v[j] = fmaxf((acc[j] + exs * hs[j]) * inv + bp[j], 0.f);
    if (p == 0) {
      float4* op = (float4*)(outv + ((size_t)node << 4));
      op[f * 2]     = make_float4(v[0], v[1], v[2], v[3]);
      op[f * 2 + 1] = make_float4(v[4], v[5], v[6], v[7]);
    }
  }

  if (do_bn) {
    float sv[8], qv[8];
    bool act = (node < n) && (p == 0);
    #pragma unroll
    for (int j = 0; j < 8; ++j) {
      sv[j] = act ? v[j] : 0.f;
      qv[j] = sv[j] * sv[j];
    }
    // fold the 16 node-groups of this wave (active lanes are l in {0,1} of
    // each 4-lane group)
    #pragma unroll
    for (int j = 0; j < 8; ++j) {
      sv[j] += __shfl_down(sv[j], 4);  qv[j] += __shfl_down(qv[j], 4);
      sv[j] += __shfl_down(sv[j], 8);  qv[j] += __shfl_down(qv[j], 8);
      sv[j] += __shfl_down(sv[j], 16); qv[j] += __shfl_down(qv[j], 16);
      sv[j] += __shfl_down(sv[j], 32); qv[j] += __shfl_down(qv[j], 32);
    }
    if ((t & 63) < 2) {
      #pragma unroll
      for (int j = 0; j < 8; ++j) {
        atomicAdd(&sbn[f * 8 + j], sv[j]);
        atomicAdd(&sbn[16 + f * 8 + j], qv[j]);
      }
    }
    __syncthreads();
    if (t < 16) atomicAdd(&bnsum[t], sbn[t]);
    else if (t < 32) atomicAdd(&bnsq[t - 16], sbn[t]);
  }
}

__global__ void k_bnp(const float* __restrict__ bnsum, const float* __restrict__ bnsq,
                      const float* __restrict__ g, const float* __restrict__ bb,
                      float* __restrict__ scale, float* __restrict__ shift, float invn) {
  int c = threadIdx.x;
  if (c >= C) return;
  float mean = bnsum[c] * invn;
  float var = bnsq[c] * invn - mean * mean;
  float s = g[c] * rsqrtf(var + 1e-5f);
  scale[c] = s; shift[c] = bb[c] - mean * s;
}

// ---------------- BN + 16x16 matmul + a_s/a_d for layer 2 ----------------
__global__ __launch_bounds__(256) void k_node2(
    const float* __restrict__ outv, const float* __restrict__ scale,
    const float* __restrict__ shift, const float* __restrict__ W2,
    const float* __restrict__ asw, const float* __restrict__ adw,
    __half* __restrict__ hh, float* __restrict__ a_s, float* __restrict__ a_d, int n) {
  __shared__ float w2s[C * C];
  if (threadIdx.x < C * C) w2s[threadIdx.x] = W2[threadIdx.x];
  __syncthreads();
  int i = blockIdx.x * 256 + threadIdx.x;
  if (i >= n) return;
  float hn[C];
  #pragma unroll
  for (int c = 0; c < C; ++c) hn[c] = outv[(size_t)i * C + c] * scale[c] + shift[c];
  float h2[C];
  #pragma unroll
  for (int j = 0; j < C; ++j) {
    float acc = 0.f;
    #pragma unroll
    for (int c = 0; c < C; ++c) acc += hn[c] * w2s[c * C + j];
    h2[j] = acc;
  }
  float hs = 0.f, hd = 0.f;
  #pragma unroll
  for (int j = 0; j < C; ++j) { hs += h2[j] * asw[j]; hd += h2[j] * adw[j]; }
  a_s[i] = hs; a_d[i] = hd;
  unsigned wbits[8];
  #pragma unroll
  for (int j = 0; j < 8; ++j) {
    __half2 hq = __floats2half2_rn(h2[2 * j], h2[2 * j + 1]);
    memcpy(&wbits[j], &hq, 4);
  }
  uint4* hp = (uint4*)(hh + (size_t)i * 16);
  hp[0] = make_uint4(wbits[0], wbits[1], wbits[2], wbits[3]);
  hp[1] = make_uint4(wbits[4], wbits[5], wbits[6], wbits[7]);
}

// ---------------- graph segment offsets ----------------
__global__ void k_gstart(const int* __restrict__ batch, int* __restrict__ gs,
                         int n, int B_) {
  int g = blockIdx.x * blockDim.x + threadIdx.x;
  if (g > B_) return;
  if (g == B_) { gs[B_] = n; return; }
  int lo = 0, hi = n;
  while (lo < hi) { int mid = (lo + hi) >> 1; if (batch[mid] < g) lo = mid + 1; else hi = mid; }
  gs[g] = lo;
}

__global__ __launch_bounds__(256) void k_xe(
    const float* __restrict__ outv, const int* __restrict__ gs,
    float* __restrict__ xe, int B_) {
  int wave = blockIdx.x * 4 + (threadIdx.x >> 6);
  if (wave >= B_) return;
  int lane = threadIdx.x & 63;
  int c = lane & 15, sub = lane >> 4;
  int base = gs[wave], end = gs[wave + 1];
  float s = 0.f;
  for (int n0 = base + sub; n0 < end; n0 += 4) s += outv[(size_t)n0 * C + c];
  s += __shfl_down(s, 32);
  s += __shfl_down(s, 16);
  if (lane < 16) xe[(size_t)wave * C + c] = s / fmaxf((float)(end - base), 1.f);
}

// ---------------- D2RL tail ----------------
__global__ __launch_bounds__(512) void k_tail_z3(
    const float* __restrict__ xe_in,
    const float* __restrict__ gL1, const float* __restrict__ bL1,
    const float* __restrict__ Wl1, const float* __restrict__ bl1,
    const float* __restrict__ gL2, const float* __restrict__ bL2,
    const float* __restrict__ Wl2, const float* __restrict__ bl2,
    const float* __restrict__ gL3, const float* __restrict__ bL3,
    const float* __restrict__ Wl3, const float* __restrict__ bl3,
    float* __restrict__ z3buf, int B_) {
  __shared__ float ssum[2 * C], ssq[2 * C], sc[2 * C], sh[2 * C];
  int t = threadIdx.x;
  float invB = 1.f / (float)B_;
  float xe[C];
  #pragma unroll
  for (int c = 0; c < C; ++c) xe[c] = xe_in[(size_t)t * C + c];

  if (t < 2 * C) { ssum[t] = 0.f; ssq[t] = 0.f; }
  __syncthreads();
  #pragma unroll
  for (int c = 0; c < C; ++c) {
    float s = xe[c], q = xe[c] * xe[c];
    for (int o = 32; o > 0; o >>= 1) { s += __shfl_down(s, o); q += __shfl_down(q, o); }
    if ((t & 63) == 0) { atomicAdd(&ssum[c], s); atomicAdd(&ssq[c], q); }
  }
  __syncthreads();
  if (t < C) {
    float mean = ssum[t] * invB, var = ssq[t] * invB - mean * mean;
    float s = gL1[t] * rsqrtf(var + 1e-5f);
    sc[t] = s; sh[t] = bL1[t] - mean * s;
  }
  __syncthreads();
  float z[C];
  #pragma unroll
  for (int j = 0; j < C; ++j) {
    float acc = bl1[j];
    #pragma unroll
    for (int c = 0; c < C; ++c) acc += (xe[c] * sc[c] + sh[c]) * Wl1[c * C + j];
    z[j] = fmaxf(acc, 0.f);
  }
  __syncthreads();

  if (t < 2 * C) { ssum[t] = 0.f; ssq[t] = 0.f; }
  __syncthreads();
  #pragma unroll
  for (int c = 0; c < C; ++c) {
    float s = z[c], q = z[c] * z[c];
    for (int o = 32; o > 0; o >>= 1) { s += __shfl_down(s, o); q += __shfl_down(q, o); }
    if ((t & 63) == 0) { atomicAdd(&ssum[c], s); atomicAdd(&ssq[c], q); }
    float s2 = xe[c], q2 = xe[c] * xe[c];
    for (int o = 32; o > 0; o >>= 1) { s2 += __shfl_down(s2, o); q2 += __shfl_down(q2, o); }
    if ((t & 63) == 0) { atomicAdd(&ssum[C + c], s2); atomicAdd(&ssq[C + c], q2); }
  }
  __syncthreads();
  if (t < 2 * C) {
    float mean = ssum[t] * invB, var = ssq[t] * invB - mean * mean;
    float s = gL2[t] * rsqrtf(var + 1e-5f);
    sc[t] = s; sh[t] = bL2[t] - mean * s;
  }
  __syncthreads();
  float z2[C];
  #pragma unroll
  for (int j = 0; j < C; ++j) {
    float acc = bl2[j];
    #pragma unroll
    for (int c = 0; c < C; ++c) acc += (z[c] * sc[c] + sh[c]) * Wl2[c * C + j];
    #pragma unroll
    for (int c = 0; c < C; ++c) acc += (xe[c] * sc[C + c] + sh[C + c]) * Wl2[(C + c) * C + j];
    z2[j] = fmaxf(acc, 0.f);
  }
  __syncthreads();

  if (t < 2 * C) { ssum[t] = 0.f; ssq[t] = 0.f; }
  __syncthreads();
  #pragma unroll
  for (int c = 0; c < C; ++c) {
    float s = z2[c], q = z2[c] * z2[c];
    for (int o = 32; o > 0; o >>= 1) { s += __shfl_down(s, o); q += __shfl_down(q, o); }
    if ((t & 63) == 0) { atomicAdd(&ssum[c], s); atomicAdd(&ssq[c], q); }
    float s2 = xe[c], q2 = xe[c] * xe[c];
    for (int o = 32; o > 0; o >>= 1) { s2 += __shfl_down(s2, o); q2 += __shfl_down(q2, o); }
    if ((t & 63) == 0) { atomicAdd(&ssum[C + c], s2); atomicAdd(&ssq[C + c], q2); }
  }
  __syncthreads();
  if (t < 2 * C) {
    float mean = ssum[t] * invB, var = ssq[t] * invB - mean * mean;
    float s = gL3[t] * rsqrtf(var + 1e-5f);
    sc[t] = s; sh[t] = bL3[t] - mean * s;
  }
  __syncthreads();
  #pragma unroll
  for (int j = 0; j < C; ++j) {
    float acc = bl3[j];
    #pragma unroll
    for (int c = 0; c < C; ++c) acc += (z2[c] * sc[c] + sh[c]) * Wl3[c * C + j];
    #pragma unroll
    for (int c = 0; c < C; ++c) acc += (xe[c] * sc[C + c] + sh[C + c]) * Wl3[(C + c) * C + j];
    z3buf[(size_t)t * C + j] = fmaxf(acc, 0.f);
  }
}

// ---------------- heads ----------------
__global__ __launch_bounds__(256) void k_heads(
    const float* __restrict__ z3buf,
    const float* __restrict__ Wx, const float* __restrict__ bx,
    const float* __restrict__ Wy, const float* __restrict__ by,
    const float* __restrict__ Wr, const float* __restrict__ br,
    float* __restrict__ out, int B_) {
  int wv = blockIdx.x * 4 + (threadIdx.x >> 6);
  if (wv >= B_) return;
  int lane = threadIdx.x & 63;
  float z[C];
  #pragma unroll
  for (int c = 0; c < C; ++c) z[c] = z3buf[(size_t)wv * C + c];

  float ax = bx[lane];
  #pragma unroll
  for (int c = 0; c < C; ++c) ax += z[c] * Wx[c * 64 + lane];
  float m = ax;
  #pragma unroll
  for (int o = 32; o > 0; o >>= 1) m = fmaxf(m, __shfl_xor(m, o));
  float e = __expf(ax - m);
  float s = e;
  #pragma unroll
  for (int o = 32; o > 0; o >>= 1) s += __shfl_xor(s, o);
  out[(size_t)wv * 64 + lane] = e / s;

  float ay = by[lane];
  #pragma unroll
  for (int c = 0; c < C; ++c) ay += z[c] * Wy[c * 64 + lane];
  m = ay;
  #pragma unroll
  for (int o = 32; o > 0; o >>= 1) m = fmaxf(m, __shfl_xor(m, o));
  e = __expf(ay - m);
  s = e;
  #pragma unroll
  for (int o = 32; o > 0; o >>= 1) s += __shfl_xor(s, o);
  out[(size_t)B_ * 64 + (size_t)wv * 64 + lane] = e / s;

  if (lane < 4) {
    float ar = br[lane];
    #pragma unroll
    for (int c = 0; c < C; ++c) ar += z[c] * Wr[c * 4 + lane];
    float mr = ar;
    mr = fmaxf(mr, __shfl_xor(mr, 1));
    mr = fmaxf(mr, __shfl_xor(mr, 2));
    float er = __expf(ar - mr);
    float sr = er;
    sr += __shfl_xor(sr, 1);
    sr += __shfl_xor(sr, 2);
    out[(size_t)B_ * 128 + (size_t)wv * 4 + lane] = er / sr;
  }
}

extern "C" void kernel_launch(void* const* d_in, const int* in_sizes, int n_in,
                              void* d_out, int out_size, void* d_ws, size_t ws_size,
                              hipStream_t stream) {
  const float* x     = (const float*)d_in[0];
  const int*   eidx  = (const int*)d_in[1];
  const float* eattr = (const float*)d_in[2];
  const int*   batch = (const int*)d_in[3];
  const float* W1  = (const float*)d_in[4];
  const float* We1 = (const float*)d_in[5];
  const float* as1 = (const float*)d_in[6];
  const float* ad1 = (const float*)d_in[7];
  const float* ae1 = (const float*)d_in[8];
  const float* b1  = (const float*)d_in[9];
  const float* g1  = (const float*)d_in[10];
  const float* bb1 = (const float*)d_in[11];
  const float* W2  = (const float*)d_in[12];
  const float* We2 = (const float*)d_in[13];
  const float* as2 = (const float*)d_in[14];
  const float* ad2 = (const float*)d_in[15];
  const float* ae2 = (const float*)d_in[16];
  const float* b2  = (const float*)d_in[17];
  const float* gL1 = (const float*)d_in[18];
  const float* bL1 = (const float*)d_in[19];
  const float* Wl1 = (const float*)d_in[20];
  const float* bl1 = (const float*)d_in[21];
  const float* gL2 = (const float*)d_in[22];
  const float* bL2 = (const float*)d_in[23];
  const float* Wl2 = (const float*)d_in[24];
  const float* bl2 = (const float*)d_in[25];
  const float* gL3 = (const float*)d_in[26];
  const float* bL3 = (const float*)d_in[27];
  const float* Wl3 = (const float*)d_in[28];
  const float* bl3 = (const float*)d_in[29];
  const float* Wx  = (const float*)d_in[30];
  const float* bx  = (const float*)d_in[31];
  const float* Wy  = (const float*)d_in[32];
  const float* by  = (const float*)d_in[33];
  const float* Wr  = (const float*)d_in[34];
  const float* br  = (const float*)d_in[35];

  int N = in_sizes[3];
  int E = in_sizes[2] / 2;
  int B = out_size / 132;

  const int* src = eidx;
  const int* dst = eidx + E;

  const int G = 256;                       // partition blocks
  int nbin = (N + 255) >> 8;               // coarse bins (dst>>8)
  int nscan = nbin * G;
  int chunk = (E + G - 1) / G;
  int nblk2 = (nscan + 511) / 512;         // scan blocks for bin table

  // ---- radix layout ----
  char* w = (char*)d_ws;
  size_t o = 0;
  auto alloc = [&](size_t bytes) { char* p = w + o; o += (bytes + 15) & ~15ull; return p; };
  uint2*  bucket = (uint2*)alloc((size_t)E * 8);
  uint2*  tmpR   = (uint2*)alloc((size_t)E * 8);
  int*    tmpD   = (int*)alloc((size_t)E * 4);
  __half* hh     = (__half*)alloc((size_t)N * C * 2);
  float*  outv   = (float*)alloc((size_t)N * C * 4);
  float*  a_s    = (float*)alloc((size_t)N * 4);
  float*  a_d    = (float*)alloc((size_t)N * 4);
  int*    offs   = (int*)alloc((size_t)(N + 4) * 4);
  int*    histT  = (int*)alloc((size_t)(nscan + 4) * 4);
  int*    histS  = (int*)alloc((size_t)(nscan + 4) * 4);
  int*    bsum   = (int*)alloc((size_t)(nblk2 + 516) * 4);
  float*  bn     = (float*)alloc(64 * 4);
  float*  xe     = (float*)alloc((size_t)B * C * 4);
  int*    gs     = (int*)alloc((size_t)(B + 4) * 4);
  float*  z3buf  = (float*)alloc((size_t)B * C * 4);
  size_t need_radix = o;

  bool radix = (need_radix <= ws_size) && (nbin <= 512) && (nblk2 <= 512);

  hipMemsetAsync(bn, 0, 32 * 4, stream);
  k_gemm1<<<(N + 63) / 64, 256, 0, stream>>>(x, W1, as1, ad1, hh, a_s, a_d, N);

  if (radix) {
    k_p1count<<<G, 256, 0, stream>>>(dst, histT, E, chunk, G, nbin);
    k_scan1<<<nblk2, 512, 0, stream>>>(histT, bsum, nscan);
    k_scan2<<<1, 512, 0, stream>>>(bsum, histS, nblk2, nscan);
    k_scan3<<<nblk2, 512, 0, stream>>>(histT, bsum, histS, nscan);
    k_p1scat<<<G, 256, 0, stream>>>(src, dst, (const float2*)eattr, histS,
                                    We1, ae1, We2, ae2, tmpR, tmpD, E, chunk, G, nbin);
    k_p2<<<nbin, 256, 0, stream>>>(tmpR, tmpD, histS, bucket, offs, G, nbin, N, E);
  } else {
    // fallback: atomic hist path (aliases rank/counts into tmpR space)
    int* rank   = (int*)tmpR;
    int* counts = (int*)tmpD;
    int nblk = (N + 511) / 512;
    int ebl = (E + 255) / 256;
    hipMemsetAsync(counts, 0, (size_t)N * 4, stream);
    k_hist_rank<<<ebl, 256, 0, stream>>>(dst, counts, rank, E);
    k_scan1<<<nblk, 512, 0, stream>>>(counts, bsum, N);
    k_scan2<<<1, 512, 0, stream>>>(bsum, offs, nblk, N);
    k_scan3<<<nblk, 512, 0, stream>>>(counts, bsum, offs, N);
    k_scatter<<<ebl, 256, 0, stream>>>(src, dst, (const float2*)eattr, offs, rank,
                                       We1, ae1, We2, ae2, bucket, E);
  }

  int nbl = (N + 255) / 256;
  k_gather<<<(N + 63) / 64, 256, 0, stream>>>(bucket, offs, a_s, a_d, hh, b1,
                                              outv, bn, bn + 16, 0, 1, N);
  k_bnp<<<1, 64, 0, stream>>>(bn, bn + 16, g1, bb1, bn + 32, bn + 48, 1.f / (float)N);
  k_node2<<<nbl, 256, 0, stream>>>(outv, bn + 32, bn + 48, W2, as2, ad2, hh, a_s, a_d, N);
  k_gather<<<(N + 63) / 64, 256, 0, stream>>>(bucket, offs, a_s, a_d, hh, b2,
                                              outv, bn, bn + 16, 1, 0, N);
  k_gstart<<<(B + 1 + 255) / 256, 256, 0, stream>>>(batch, gs, N, B);
  k_xe<<<(B + 3) / 4, 256, 0, stream>>>(outv, gs, xe, B);
  k_tail_z3<<<1, B, 0, stream>>>(xe, gL1, bL1, Wl1, bl1, gL2, bL2, Wl2, bl2,
                                 gL3, bL3, Wl3, bl3, z3buf, B);
  k_heads<<<(B + 3) / 4, 256, 0, stream>>>(z3buf, Wx, bx, Wy, by, Wr, br,
                                           (float*)d_out, B);
}